// Round 1
// baseline (140.323 us; speedup 1.0000x reference)
//
#include <hip/hip_runtime.h>
#include <math.h>

// Problem constants (from reference)
#define NB 128
#define NT 256
#define NI 256
#define NF 256
#define NROWS (NB * NT)   // 32768 independent rows (see analysis below)
#define RPB 16            // rows per block
#define NTHREADS 256

// Why rows are independent:
//   alpha = exp(-50) ~ 1.93e-22. In fp32 AND fp64, (1-alpha) rounds to 1.0
//   exactly, and alpha*v_prev (<=1e-21) is below 0.5*ulp(cur) for any |cur|
//   relevant to the spike decision (threshold 0.5). Hence v_mem(t) == cur(t)
//   in the reference's own arithmetic, and the scan decouples elementwise.
// Why fp64 accumulation:
//   s = Heaviside(cur - 0.5); a single flipped spike costs ~2.5 absmax error
//   vs a 0.067 threshold. fp64 dot error ~1e-15 makes flips vs the numpy
//   reference astronomically unlikely; fp32 reordering error (~1e-6) would
//   flip several of the 8.4M elements.
// LayerNorm of a binary vector collapses: mu = k/256 (exact), var = mu(1-mu).

__global__ void lif_fused_f64(const float* __restrict__ spikes,   // [NROWS, NI]
                              const float* __restrict__ W,        // [NI, NF]
                              const float* __restrict__ bias,     // [NF]
                              const float* __restrict__ ln_scale, // [NT, NF]
                              const float* __restrict__ ln_bias,  // [NT, NF]
                              float* __restrict__ out)            // [NROWS, NF]
{
    __shared__ double sd[RPB][NI];   // 32 KB: spike rows as double (broadcast reads)
    __shared__ int wcnt[4][RPB];     // per-wave spike counts

    const int tid = threadIdx.x;
    const int row0 = blockIdx.x * RPB;

    // Stage 16 spike rows -> LDS as double (coalesced fp32 loads, one cvt each)
    #pragma unroll
    for (int r = 0; r < RPB; ++r)
        sd[r][tid] = (double)spikes[(size_t)(row0 + r) * NI + tid];
    __syncthreads();

    const int f = tid;               // this thread owns output column f
    const double bv = (double)bias[f];

    double acc[RPB];
    #pragma unroll
    for (int r = 0; r < RPB; ++r) acc[r] = 0.0;

    const float* wp = W + f;
    // Inner product over i: 1 coalesced W load per i (L2-resident, 256 KB total),
    // 16 broadcast LDS reads + 16 DFMA. Unroll by 2 so adjacent sd[r][i],
    // sd[r][i+1] merge into ds_read_b128.
    for (int i = 0; i < NI; i += 2) {
        double w0 = (double)wp[(size_t)i * NF];
        double w1 = (double)wp[(size_t)(i + 1) * NF];
        #pragma unroll
        for (int r = 0; r < RPB; ++r) {
            acc[r] += sd[r][i] * w0;
            acc[r] += sd[r][i + 1] * w1;
        }
    }

    // Spike decision + per-row counts (wave64 ballot, then cross-wave combine)
    const int lane = tid & 63;
    const int wid = tid >> 6;
    bool sb[RPB];
    #pragma unroll
    for (int r = 0; r < RPB; ++r) {
        double v = acc[r] + bv;                 // currents = dot + b; v_mem == cur
        sb[r] = (v - 0.5) > 0.0;                // spike (strict >, matches ref)
        unsigned long long m = __ballot(sb[r]);
        if (lane == 0) wcnt[wid][r] = __popcll(m);
    }
    __syncthreads();

    // Closed-form LayerNorm epilogue
    #pragma unroll
    for (int r = 0; r < RPB; ++r) {
        const int row = row0 + r;
        const int t = row & (NT - 1);           // row = b*NT + t
        const int k = wcnt[0][r] + wcnt[1][r] + wcnt[2][r] + wcnt[3][r];
        const double mu = (double)k * (1.0 / 256.0);      // exact
        const double var = mu * (1.0 - mu);               // exact form for binary s
        const float rinv = (float)(1.0 / sqrt(var + 1e-6));
        const float g = ln_scale[t * NF + f];
        const float be = ln_bias[t * NF + f];
        const float sv = sb[r] ? 1.0f : 0.0f;
        const float muf = (float)mu;                      // exact in fp32 (k/256)
        out[(size_t)row * NF + f] = (sv - muf) * rinv * g + be;
    }
}

extern "C" void kernel_launch(void* const* d_in, const int* in_sizes, int n_in,
                              void* d_out, int out_size, void* d_ws, size_t ws_size,
                              hipStream_t stream) {
    const float* spikes   = (const float*)d_in[0];
    const float* W        = (const float*)d_in[1];
    const float* bias     = (const float*)d_in[2];
    const float* ln_scale = (const float*)d_in[3];
    const float* ln_bias  = (const float*)d_in[4];
    float* out = (float*)d_out;

    dim3 grid(NROWS / RPB);   // 2048 blocks
    dim3 block(NTHREADS);
    hipLaunchKernelGGL(lif_fused_f64, grid, block, 0, stream,
                       spikes, W, bias, ln_scale, ln_bias, out);
}